// Round 11
// baseline (5131.364 us; speedup 1.0000x reference)
//
#include <hip/hip_runtime.h>

// CfC actor-critic forward: B=256, T=1024, OBS=32, H=128, A=8.
// R11: phase ping-pong. 64 blocks x 16 waves; two independent 2-row groups
// per block with OPPOSITE phase schedules (interval1: A-ph1 || B-ph2;
// interval2: A-ph2 || B-ph1(t+1)). Each SIMD hosts 2 A-waves + 2 B-waves ->
// independent chains at different phases hide each other's LDS/MFMA latency
// (R6-R10 lockstep exposed ~870 of 1330 cyc/interval as unhidden stall).
// Weights identical per wg across groups; per-wave work same as R10.

typedef _Float16 half8 __attribute__((ext_vector_type(8)));
typedef float f32x4 __attribute__((ext_vector_type(4)));

#define T_STEPS 1024
#define OBS 32
#define H 128
#define A_DIM 8
#define NT 1024      // 16 waves
#define NBLK 64
#define GR 2         // rows per group (2 groups x 2 rows = 4 rows/block)

#define ZIN_P 164    // stride 82 words (mod 32 = 18) -> <=2-way banks
#define ZF_P 132     // stride 66 words (mod 32 = 2)

__device__ __forceinline__ float fexp2(float x) { return __builtin_amdgcn_exp2f(x); }
__device__ __forceinline__ float frcp(float x) { return __builtin_amdgcn_rcpf(x); }

// LDS-visibility barrier (no vmcnt drain; R10-verified safe)
__device__ __forceinline__ void sync_lds() {
    __builtin_amdgcn_sched_barrier(0);
    asm volatile("s_waitcnt lgkmcnt(0)" ::: "memory");
    __builtin_amdgcn_s_barrier();
    __builtin_amdgcn_sched_barrier(0);
}

__device__ __forceinline__ void ph1_body(
    _Float16 (*zinG)[ZIN_P], _Float16 (*zfG)[ZF_P],
    int lo, int hi, int colB, int wg,
    const half8 (&Bb)[5], float bbv,
    const half8 (&Bh)[4], float bh,
    int head_step, int b0g,
    float* __restrict__ out_mean, float* __restrict__ out_value)
{
    half8 A0 = *(const half8*)&zinG[lo][0 * 32 + hi * 8];
    half8 A1 = *(const half8*)&zinG[lo][1 * 32 + hi * 8];
    half8 A2 = *(const half8*)&zinG[lo][2 * 32 + hi * 8];
    half8 A3 = *(const half8*)&zinG[lo][3 * 32 + hi * 8];
    half8 A4 = *(const half8*)&zinG[lo][4 * 32 + hi * 8];
    f32x4 az0 = {bbv, bbv, bbv, bbv};
    f32x4 az1 = {0.f, 0.f, 0.f, 0.f};
    az0 = __builtin_amdgcn_mfma_f32_16x16x32_f16(A0, Bb[0], az0, 0, 0, 0);
    az1 = __builtin_amdgcn_mfma_f32_16x16x32_f16(A1, Bb[1], az1, 0, 0, 0);
    az0 = __builtin_amdgcn_mfma_f32_16x16x32_f16(A2, Bb[2], az0, 0, 0, 0);
    az1 = __builtin_amdgcn_mfma_f32_16x16x32_f16(A3, Bb[3], az1, 0, 0, 0);
    az0 = __builtin_amdgcn_mfma_f32_16x16x32_f16(A4, Bb[4], az0, 0, 0, 0);

    // heads on this group's resident h (A1..A4 are exactly the h k-subtiles)
    if (wg == 7 && head_step >= 0) {
        f32x4 acch = {bh, bh, bh, bh};
        acch = __builtin_amdgcn_mfma_f32_16x16x32_f16(A1, Bh[0], acch, 0, 0, 0);
        acch = __builtin_amdgcn_mfma_f32_16x16x32_f16(A2, Bh[1], acch, 0, 0, 0);
        acch = __builtin_amdgcn_mfma_f32_16x16x32_f16(A3, Bh[2], acch, 0, 0, 0);
        acch = __builtin_amdgcn_mfma_f32_16x16x32_f16(A4, Bh[3], acch, 0, 0, 0);
        if (hi == 0 && lo < 9) {
#pragma unroll
            for (int j = 0; j < GR; ++j) {
                if (lo < 8) out_mean[((size_t)(b0g + j) * T_STEPS + head_step) * A_DIM + lo] = acch[j];
                else        out_value[(size_t)(b0g + j) * T_STEPS + head_step] = acch[j];
            }
        }
    }

    // z-act: 1.7159*tanh(0.666x) = 1.7159 - 3.4318/(2^(1.9216697x)+1)
#pragma unroll
    for (int j = 0; j < 4; ++j) {
        float s = az0[j] + az1[j];
        float r = frcp(fexp2(1.9216697f * s) + 1.0f);
        zfG[hi * 4 + j][colB] = (_Float16)fmaf(-3.4318f, r, 1.7159f);
    }
}

__device__ __forceinline__ void ph2_body(
    _Float16 (*zinG)[ZIN_P], _Float16 (*zfG)[ZF_P],
    int lo, int hi, int colB, int wg,
    const half8 (&Bg0)[4], const half8 (&Bg1)[4], const half8 (&Bg2)[4],
    float bg1, float bg2, float bg3,
    int t, int rx, int cx, const float* __restrict__ obsrow,
    float& oxA, float& oxB)
{
    half8 Z0 = *(const half8*)&zfG[lo][0 * 32 + hi * 8];
    half8 Z1 = *(const half8*)&zfG[lo][1 * 32 + hi * 8];
    half8 Z2 = *(const half8*)&zfG[lo][2 * 32 + hi * 8];
    half8 Z3 = *(const half8*)&zfG[lo][3 * 32 + hi * 8];
    f32x4 a1 = {bg1, bg1, bg1, bg1};
    f32x4 a2 = {bg2, bg2, bg2, bg2};
    f32x4 a3 = {bg3, bg3, bg3, bg3};
    a1 = __builtin_amdgcn_mfma_f32_16x16x32_f16(Z0, Bg0[0], a1, 0, 0, 0);
    a2 = __builtin_amdgcn_mfma_f32_16x16x32_f16(Z0, Bg1[0], a2, 0, 0, 0);
    a3 = __builtin_amdgcn_mfma_f32_16x16x32_f16(Z0, Bg2[0], a3, 0, 0, 0);
    a1 = __builtin_amdgcn_mfma_f32_16x16x32_f16(Z1, Bg0[1], a1, 0, 0, 0);
    a2 = __builtin_amdgcn_mfma_f32_16x16x32_f16(Z1, Bg1[1], a2, 0, 0, 0);
    a3 = __builtin_amdgcn_mfma_f32_16x16x32_f16(Z1, Bg2[1], a3, 0, 0, 0);
    a1 = __builtin_amdgcn_mfma_f32_16x16x32_f16(Z2, Bg0[2], a1, 0, 0, 0);
    a2 = __builtin_amdgcn_mfma_f32_16x16x32_f16(Z2, Bg1[2], a2, 0, 0, 0);
    a3 = __builtin_amdgcn_mfma_f32_16x16x32_f16(Z2, Bg2[2], a3, 0, 0, 0);
    a1 = __builtin_amdgcn_mfma_f32_16x16x32_f16(Z3, Bg0[3], a1, 0, 0, 0);
    a2 = __builtin_amdgcn_mfma_f32_16x16x32_f16(Z3, Bg1[3], a2, 0, 0, 0);
    a3 = __builtin_amdgcn_mfma_f32_16x16x32_f16(Z3, Bg2[3], a3, 0, 0, 0);

#pragma unroll
    for (int j = 0; j < 4; ++j) {
        float r1 = frcp(fexp2(2.8853901f * a1[j]) + 1.0f);
        float ff1 = fmaf(-2.0f, r1, 1.0f);
        float r2 = frcp(fexp2(2.8853901f * a2[j]) + 1.0f);
        float ff2 = fmaf(-2.0f, r2, 1.0f);
        float ti = frcp(1.0f + fexp2(-1.44269504f * a3[j]));
        zinG[hi * 4 + j][32 + colB] = (_Float16)(ff1 + ti * (ff2 - ff1));
    }

    // x(t+1) write + 2-deep ring refill (this group's wg==0 wave)
    if (wg == 0) {
        if (t + 1 < T_STEPS) zinG[rx][cx] = (_Float16)oxA;
        oxA = oxB;
        const int tf = t + 3;
        oxB = (tf < T_STEPS) ? obsrow[(size_t)tf * OBS + cx] : 0.0f;
    }
}

__global__ void __launch_bounds__(NT) cfc_kernel(
    const float* __restrict__ obs,
    const float* __restrict__ Wb,  const float* __restrict__ bb,
    const float* __restrict__ Wff1, const float* __restrict__ bff1,
    const float* __restrict__ Wff2, const float* __restrict__ bff2,
    const float* __restrict__ Wta, const float* __restrict__ bta,
    const float* __restrict__ Wtb, const float* __restrict__ btb,
    const float* __restrict__ Wa,  const float* __restrict__ ba,
    const float* __restrict__ Wc,  const float* __restrict__ bc,
    float* __restrict__ out_mean, float* __restrict__ out_value)
{
    const int tid = threadIdx.x;
    const int w = tid >> 6, l = tid & 63;
    const int g = w >> 3, wg = w & 7;        // group, wave-in-group
    const int lo = l & 15, hi = l >> 4;
    const int b0g = blockIdx.x * 4 + g * GR;

    __shared__ _Float16 zin[2][16][ZIN_P];   // per-group [x_t | h]
    __shared__ _Float16 zf[2][16][ZF_P];     // per-group z

    // ---------------- preload B-fragments (shared across groups) ----------
    const int colB = wg * 16 + lo;

    half8 Bb[5];
#pragma unroll
    for (int ks = 0; ks < 5; ++ks)
#pragma unroll
        for (int j = 0; j < 8; ++j) {
            int k = ks * 32 + hi * 8 + j;
            Bb[ks][j] = (_Float16)Wb[k * H + colB];
        }
    const float bbv = bb[colB];

    half8 Bg0[4], Bg1[4], Bg2[4];
#pragma unroll
    for (int ks = 0; ks < 4; ++ks)
#pragma unroll
        for (int j = 0; j < 8; ++j) {
            int k = ks * 32 + hi * 8 + j;
            Bg0[ks][j] = (_Float16)Wff1[k * H + colB];
            Bg1[ks][j] = (_Float16)Wff2[k * H + colB];
            Bg2[ks][j] = (_Float16)(Wta[k * H + colB] + Wtb[k * H + colB]);
        }
    const float bg1 = bff1[colB], bg2 = bff2[colB], bg3 = bta[colB] + btb[colB];

    half8 Bh[4];
    float bh = 0.f;
    if (wg == 7) {
#pragma unroll
        for (int ks = 0; ks < 4; ++ks)
#pragma unroll
            for (int j = 0; j < 8; ++j) {
                int k = ks * 32 + hi * 8 + j;
                float v = (lo < 8) ? Wa[k * A_DIM + lo] : ((lo == 8) ? Wc[k] : 0.0f);
                Bh[ks][j] = (_Float16)v;
            }
        bh = (lo < 8) ? ba[lo] : ((lo == 8) ? bc[0] : 0.0f);
    }

    // ---------------- x ring (wg==0 wave of each group) ----------------
    const int rx = l >> 5, cx = l & 31;      // row 0..1, col 0..31
    const float* obsrow = obs + ((size_t)(b0g + rx) * T_STEPS) * OBS;
    float oxA = 0.f, oxB = 0.f;

    // ---------------- init LDS ----------------
    for (int i = tid; i < 2 * 16 * ZIN_P; i += NT) (&zin[0][0][0])[i] = (_Float16)0.0f;
    __syncthreads();
    if (wg == 0) {
        zin[g][rx][cx] = (_Float16)obsrow[cx];      // x(0)
        oxA = obsrow[OBS + cx];                      // x(1)
        oxB = obsrow[2 * OBS + cx];                  // x(2)
    }
    __syncthreads();

    // ---------------- prime: group B computes ph1(0) ----------------
    if (g == 1)
        ph1_body(zin[1], zf[1], lo, hi, colB, wg, Bb, bbv, Bh, bh,
                 -1, b0g, out_mean, out_value);
    __syncthreads();

    // ================= main loop: 2 mixed-phase intervals/step =============
    for (int t = 0; t < T_STEPS; ++t) {
        // interval 1: A: ph1(t) + heads(t-1) || B: ph2(t) + x-write
        if (g == 0)
            ph1_body(zin[0], zf[0], lo, hi, colB, wg, Bb, bbv, Bh, bh,
                     t - 1, b0g, out_mean, out_value);
        else
            ph2_body(zin[1], zf[1], lo, hi, colB, wg, Bg0, Bg1, Bg2,
                     bg1, bg2, bg3, t, rx, cx, obsrow, oxA, oxB);
        sync_lds();

        // interval 2: A: ph2(t) + x-write || B: ph1(t+1) + heads(t)
        if (g == 0)
            ph2_body(zin[0], zf[0], lo, hi, colB, wg, Bg0, Bg1, Bg2,
                     bg1, bg2, bg3, t, rx, cx, obsrow, oxA, oxB);
        else
            ph1_body(zin[1], zf[1], lo, hi, colB, wg, Bb, bbv, Bh, bh,
                     t, b0g, out_mean, out_value);
        sync_lds();
    }

    // ---- epilogue: group A heads for s = T-1 ----
    if (g == 0 && wg == 7) {
        half8 A1 = *(const half8*)&zin[0][lo][32 + hi * 8];
        half8 A2 = *(const half8*)&zin[0][lo][64 + hi * 8];
        half8 A3 = *(const half8*)&zin[0][lo][96 + hi * 8];
        half8 A4 = *(const half8*)&zin[0][lo][128 + hi * 8];
        f32x4 acch = {bh, bh, bh, bh};
        acch = __builtin_amdgcn_mfma_f32_16x16x32_f16(A1, Bh[0], acch, 0, 0, 0);
        acch = __builtin_amdgcn_mfma_f32_16x16x32_f16(A2, Bh[1], acch, 0, 0, 0);
        acch = __builtin_amdgcn_mfma_f32_16x16x32_f16(A3, Bh[2], acch, 0, 0, 0);
        acch = __builtin_amdgcn_mfma_f32_16x16x32_f16(A4, Bh[3], acch, 0, 0, 0);
        if (hi == 0 && lo < 9) {
#pragma unroll
            for (int j = 0; j < GR; ++j) {
                if (lo < 8) out_mean[((size_t)(b0g + j) * T_STEPS + (T_STEPS - 1)) * A_DIM + lo] = acch[j];
                else        out_value[(size_t)(b0g + j) * T_STEPS + (T_STEPS - 1)] = acch[j];
            }
        }
    }
}

extern "C" void kernel_launch(void* const* d_in, const int* in_sizes, int n_in,
                              void* d_out, int out_size, void* d_ws, size_t ws_size,
                              hipStream_t stream) {
    (void)in_sizes; (void)n_in; (void)d_ws; (void)ws_size; (void)out_size;
    const float* obs  = (const float*)d_in[0];
    const float* Wb   = (const float*)d_in[1];
    const float* bb   = (const float*)d_in[2];
    const float* Wff1 = (const float*)d_in[3];
    const float* bff1 = (const float*)d_in[4];
    const float* Wff2 = (const float*)d_in[5];
    const float* bff2 = (const float*)d_in[6];
    const float* Wta  = (const float*)d_in[7];
    const float* bta  = (const float*)d_in[8];
    const float* Wtb  = (const float*)d_in[9];
    const float* btb  = (const float*)d_in[10];
    const float* Wa   = (const float*)d_in[11];
    const float* ba   = (const float*)d_in[12];
    const float* Wc   = (const float*)d_in[13];
    const float* bc   = (const float*)d_in[14];
    float* out = (float*)d_out;
    float* out_mean  = out;
    float* out_value = out + (size_t)256 * 1024 * 8;

    cfc_kernel<<<dim3(NBLK), dim3(NT), 0, stream>>>(
        obs, Wb, bb, Wff1, bff1, Wff2, bff2, Wta, bta, Wtb, btb,
        Wa, ba, Wc, bc, out_mean, out_value);
}

// Round 12
// 2624.120 us; speedup vs baseline: 1.9555x; 1.9555x over previous
//
#include <hip/hip_runtime.h>

// CfC actor-critic forward: B=256, T=1024, OBS=32, H=128, A=8.
// R12: ping-pong retry. R11's failure was the ALLOCATOR (launch_bounds(1024)
// -> 8 waves/SIMD target -> 64-VGPR cap -> weight spill, 30/40MB scratch
// traffic), not the concept. Pin occupancy: flat_work_group_size(1024,1024) +
// waves_per_eu(4,4) -> 128-VGPR budget; per-wave live set == R10's (116).
// Two 2-row groups per block at OPPOSITE phases (A: ph1 on even intervals,
// B on odd; B primed via iv=-1), one lgkm-only barrier per interval. Each
// SIMD hosts 2 A-waves + 2 B-waves -> different-phase stall interleave.

typedef _Float16 half8 __attribute__((ext_vector_type(8)));
typedef float f32x4 __attribute__((ext_vector_type(4)));

#define T_STEPS 1024
#define OBS 32
#define H 128
#define A_DIM 8
#define NT 1024      // 16 waves: group A = waves 0-7, group B = waves 8-15
#define NBLK 64
#define GR 2         // rows per group

#define ZIN_P 164    // stride 82 words (mod 32 = 18) -> <=2-way banks
#define ZF_P 132     // stride 66 words (mod 32 = 2)

__device__ __forceinline__ float fexp2(float x) { return __builtin_amdgcn_exp2f(x); }
__device__ __forceinline__ float frcp(float x) { return __builtin_amdgcn_rcpf(x); }

// LDS-visibility barrier (no vmcnt drain; validated R10)
__device__ __forceinline__ void sync_lds() {
    __builtin_amdgcn_sched_barrier(0);
    asm volatile("s_waitcnt lgkmcnt(0)" ::: "memory");
    __builtin_amdgcn_s_barrier();
    __builtin_amdgcn_sched_barrier(0);
}

__attribute__((amdgpu_flat_work_group_size(NT, NT), amdgpu_waves_per_eu(4, 4)))
__global__ void cfc_kernel(
    const float* __restrict__ obs,
    const float* __restrict__ Wb,  const float* __restrict__ bb,
    const float* __restrict__ Wff1, const float* __restrict__ bff1,
    const float* __restrict__ Wff2, const float* __restrict__ bff2,
    const float* __restrict__ Wta, const float* __restrict__ bta,
    const float* __restrict__ Wtb, const float* __restrict__ btb,
    const float* __restrict__ Wa,  const float* __restrict__ ba,
    const float* __restrict__ Wc,  const float* __restrict__ bc,
    float* __restrict__ out_mean, float* __restrict__ out_value)
{
    const int tid = threadIdx.x;
    const int w = tid >> 6, l = tid & 63;
    const int g = w >> 3, wg = w & 7;        // group, wave-in-group
    const int lo = l & 15, hi = l >> 4;
    const int b0g = blockIdx.x * 4 + g * GR;

    __shared__ _Float16 zin[2][16][ZIN_P];   // per-group [x_t | h]
    __shared__ _Float16 zf[2][16][ZF_P];     // per-group z

    // ---------------- preload B-fragments (same content both groups) -------
    const int colB = wg * 16 + lo;

    half8 Bb[5];
#pragma unroll
    for (int ks = 0; ks < 5; ++ks)
#pragma unroll
        for (int j = 0; j < 8; ++j) {
            int k = ks * 32 + hi * 8 + j;
            Bb[ks][j] = (_Float16)Wb[k * H + colB];
        }
    const float bbv = bb[colB];

    half8 Bg0[4], Bg1[4], Bg2[4];
#pragma unroll
    for (int ks = 0; ks < 4; ++ks)
#pragma unroll
        for (int j = 0; j < 8; ++j) {
            int k = ks * 32 + hi * 8 + j;
            Bg0[ks][j] = (_Float16)Wff1[k * H + colB];
            Bg1[ks][j] = (_Float16)Wff2[k * H + colB];
            Bg2[ks][j] = (_Float16)(Wta[k * H + colB] + Wtb[k * H + colB]);
        }
    const float bg1 = bff1[colB], bg2 = bff2[colB], bg3 = bta[colB] + btb[colB];

    half8 Bh[4];
    float bh = 0.f;
    if (wg == 7) {
#pragma unroll
        for (int ks = 0; ks < 4; ++ks)
#pragma unroll
            for (int j = 0; j < 8; ++j) {
                int k = ks * 32 + hi * 8 + j;
                float v = (lo < 8) ? Wa[k * A_DIM + lo] : ((lo == 8) ? Wc[k] : 0.0f);
                Bh[ks][j] = (_Float16)v;
            }
        bh = (lo < 8) ? ba[lo] : ((lo == 8) ? bc[0] : 0.0f);
    }

    // ---------------- x ring (wg==0 wave of each group; 2 rows) -----------
    const int rx = l >> 5, cx = l & 31;
    const float* obsrow = obs + ((size_t)(b0g + rx) * T_STEPS) * OBS;
    float oxA = 0.f, oxB = 0.f;

    // ---------------- init LDS ----------------
    for (int i = tid; i < 2 * 16 * ZIN_P; i += NT) (&zin[0][0][0])[i] = (_Float16)0.0f;
    __syncthreads();
    if (wg == 0) {
        zin[g][rx][cx] = (_Float16)obsrow[cx];   // x(0)
        oxA = obsrow[OBS + cx];                  // x(1)
        oxB = obsrow[2 * OBS + cx];              // x(2)
    }
    __syncthreads();

    // ================= interval loop =================
    // A (g=0): ph1 on even iv (t=iv/2),      ph2 on odd iv (t=iv/2).
    // B (g=1): ph1 on odd iv (t=(iv+1)/2),   ph2 on even iv (t=iv/2).
    // iv=-1: B runs ph1(0) (prime); A's ph2 guarded out by t<0.
    for (int iv = -1; iv < 2 * T_STEPS; ++iv) {
        const bool doP1 = ((iv ^ g) & 1) == 0;
        if (doP1) {
            const int t = (iv + g) >> 1;     // ph1 time index (A:<=1023, B:<=1024)
            half8 A0 = *(const half8*)&zin[g][lo][0 * 32 + hi * 8];
            half8 A1 = *(const half8*)&zin[g][lo][1 * 32 + hi * 8];
            half8 A2 = *(const half8*)&zin[g][lo][2 * 32 + hi * 8];
            half8 A3 = *(const half8*)&zin[g][lo][3 * 32 + hi * 8];
            half8 A4 = *(const half8*)&zin[g][lo][4 * 32 + hi * 8];
            f32x4 az0 = {bbv, bbv, bbv, bbv};
            f32x4 az1 = {0.f, 0.f, 0.f, 0.f};
            az0 = __builtin_amdgcn_mfma_f32_16x16x32_f16(A0, Bb[0], az0, 0, 0, 0);
            az1 = __builtin_amdgcn_mfma_f32_16x16x32_f16(A1, Bb[1], az1, 0, 0, 0);
            az0 = __builtin_amdgcn_mfma_f32_16x16x32_f16(A2, Bb[2], az0, 0, 0, 0);
            az1 = __builtin_amdgcn_mfma_f32_16x16x32_f16(A3, Bb[3], az1, 0, 0, 0);
            az0 = __builtin_amdgcn_mfma_f32_16x16x32_f16(A4, Bb[4], az0, 0, 0, 0);

            // heads on h(t-1) (A1..A4 are exactly the h k-subtiles)
            if (wg == 7 && t >= 1) {
                f32x4 acch = {bh, bh, bh, bh};
                acch = __builtin_amdgcn_mfma_f32_16x16x32_f16(A1, Bh[0], acch, 0, 0, 0);
                acch = __builtin_amdgcn_mfma_f32_16x16x32_f16(A2, Bh[1], acch, 0, 0, 0);
                acch = __builtin_amdgcn_mfma_f32_16x16x32_f16(A3, Bh[2], acch, 0, 0, 0);
                acch = __builtin_amdgcn_mfma_f32_16x16x32_f16(A4, Bh[3], acch, 0, 0, 0);
                if (hi == 0 && lo < 9) {
                    const int s_ = t - 1;
#pragma unroll
                    for (int j = 0; j < GR; ++j) {
                        if (lo < 8) out_mean[((size_t)(b0g + j) * T_STEPS + s_) * A_DIM + lo] = acch[j];
                        else        out_value[(size_t)(b0g + j) * T_STEPS + s_] = acch[j];
                    }
                }
            }

            // z-act: 1.7159*tanh(0.666x) = 1.7159 - 3.4318/(2^(1.9216697x)+1)
#pragma unroll
            for (int j = 0; j < 4; ++j) {
                float s = az0[j] + az1[j];
                float r = frcp(fexp2(1.9216697f * s) + 1.0f);
                zf[g][hi * 4 + j][colB] = (_Float16)fmaf(-3.4318f, r, 1.7159f);
            }
        } else {
            const int t = iv >> 1;           // ph2 time index (skip t<0: A at iv=-1)
            if (t >= 0) {
                half8 Z0 = *(const half8*)&zf[g][lo][0 * 32 + hi * 8];
                half8 Z1 = *(const half8*)&zf[g][lo][1 * 32 + hi * 8];
                half8 Z2 = *(const half8*)&zf[g][lo][2 * 32 + hi * 8];
                half8 Z3 = *(const half8*)&zf[g][lo][3 * 32 + hi * 8];
                f32x4 a1 = {bg1, bg1, bg1, bg1};
                f32x4 a2 = {bg2, bg2, bg2, bg2};
                f32x4 a3 = {bg3, bg3, bg3, bg3};
                a1 = __builtin_amdgcn_mfma_f32_16x16x32_f16(Z0, Bg0[0], a1, 0, 0, 0);
                a2 = __builtin_amdgcn_mfma_f32_16x16x32_f16(Z0, Bg1[0], a2, 0, 0, 0);
                a3 = __builtin_amdgcn_mfma_f32_16x16x32_f16(Z0, Bg2[0], a3, 0, 0, 0);
                a1 = __builtin_amdgcn_mfma_f32_16x16x32_f16(Z1, Bg0[1], a1, 0, 0, 0);
                a2 = __builtin_amdgcn_mfma_f32_16x16x32_f16(Z1, Bg1[1], a2, 0, 0, 0);
                a3 = __builtin_amdgcn_mfma_f32_16x16x32_f16(Z1, Bg2[1], a3, 0, 0, 0);
                a1 = __builtin_amdgcn_mfma_f32_16x16x32_f16(Z2, Bg0[2], a1, 0, 0, 0);
                a2 = __builtin_amdgcn_mfma_f32_16x16x32_f16(Z2, Bg1[2], a2, 0, 0, 0);
                a3 = __builtin_amdgcn_mfma_f32_16x16x32_f16(Z2, Bg2[2], a3, 0, 0, 0);
                a1 = __builtin_amdgcn_mfma_f32_16x16x32_f16(Z3, Bg0[3], a1, 0, 0, 0);
                a2 = __builtin_amdgcn_mfma_f32_16x16x32_f16(Z3, Bg1[3], a2, 0, 0, 0);
                a3 = __builtin_amdgcn_mfma_f32_16x16x32_f16(Z3, Bg2[3], a3, 0, 0, 0);

#pragma unroll
                for (int j = 0; j < 4; ++j) {
                    float r1 = frcp(fexp2(2.8853901f * a1[j]) + 1.0f);
                    float ff1 = fmaf(-2.0f, r1, 1.0f);
                    float r2 = frcp(fexp2(2.8853901f * a2[j]) + 1.0f);
                    float ff2 = fmaf(-2.0f, r2, 1.0f);
                    float ti = frcp(1.0f + fexp2(-1.44269504f * a3[j]));
                    zin[g][hi * 4 + j][32 + colB] = (_Float16)(ff1 + ti * (ff2 - ff1));
                }

                // x(t+1) write + 2-deep ring refill (this group's wg==0 wave)
                if (wg == 0) {
                    if (t + 1 < T_STEPS) zin[g][rx][cx] = (_Float16)oxA;
                    oxA = oxB;
                    const int tf = t + 3;
                    oxB = (tf < T_STEPS) ? obsrow[(size_t)tf * OBS + cx] : 0.0f;
                }
            }
        }
        sync_lds();
    }

    // ---- epilogue: group A heads for s = T-1 (B's covered in-loop) ----
    if (g == 0 && wg == 7) {
        half8 A1 = *(const half8*)&zin[0][lo][32 + 0 * 32 + hi * 8];
        half8 A2 = *(const half8*)&zin[0][lo][32 + 1 * 32 + hi * 8];
        half8 A3 = *(const half8*)&zin[0][lo][32 + 2 * 32 + hi * 8];
        half8 A4 = *(const half8*)&zin[0][lo][32 + 3 * 32 + hi * 8];
        f32x4 acch = {bh, bh, bh, bh};
        acch = __builtin_amdgcn_mfma_f32_16x16x32_f16(A1, Bh[0], acch, 0, 0, 0);
        acch = __builtin_amdgcn_mfma_f32_16x16x32_f16(A2, Bh[1], acch, 0, 0, 0);
        acch = __builtin_amdgcn_mfma_f32_16x16x32_f16(A3, Bh[2], acch, 0, 0, 0);
        acch = __builtin_amdgcn_mfma_f32_16x16x32_f16(A4, Bh[3], acch, 0, 0, 0);
        if (hi == 0 && lo < 9) {
#pragma unroll
            for (int j = 0; j < GR; ++j) {
                if (lo < 8) out_mean[((size_t)(b0g + j) * T_STEPS + (T_STEPS - 1)) * A_DIM + lo] = acch[j];
                else        out_value[(size_t)(b0g + j) * T_STEPS + (T_STEPS - 1)] = acch[j];
            }
        }
    }
}

extern "C" void kernel_launch(void* const* d_in, const int* in_sizes, int n_in,
                              void* d_out, int out_size, void* d_ws, size_t ws_size,
                              hipStream_t stream) {
    (void)in_sizes; (void)n_in; (void)d_ws; (void)ws_size; (void)out_size;
    const float* obs  = (const float*)d_in[0];
    const float* Wb   = (const float*)d_in[1];
    const float* bb   = (const float*)d_in[2];
    const float* Wff1 = (const float*)d_in[3];
    const float* bff1 = (const float*)d_in[4];
    const float* Wff2 = (const float*)d_in[5];
    const float* bff2 = (const float*)d_in[6];
    const float* Wta  = (const float*)d_in[7];
    const float* bta  = (const float*)d_in[8];
    const float* Wtb  = (const float*)d_in[9];
    const float* btb  = (const float*)d_in[10];
    const float* Wa   = (const float*)d_in[11];
    const float* ba   = (const float*)d_in[12];
    const float* Wc   = (const float*)d_in[13];
    const float* bc   = (const float*)d_in[14];
    float* out = (float*)d_out;
    float* out_mean  = out;
    float* out_value = out + (size_t)256 * 1024 * 8;

    cfc_kernel<<<dim3(NBLK), dim3(NT), 0, stream>>>(
        obs, Wb, bb, Wff1, bff1, Wff2, bff2, Wta, bta, Wtb, btb,
        Wa, ba, Wc, bc, out_mean, out_value);
}

// Round 13
// 2074.503 us; speedup vs baseline: 2.4735x; 1.2649x over previous
//
#include <hip/hip_runtime.h>

// CfC actor-critic forward: B=256, T=1024, OBS=32, H=128, A=8.
// R13: ping-pong at NT=512 (the allocator-honorable config).
// 8 waves = 2 groups x 4 waves; each group owns 2 batch rows; each wave owns
// 32 output cols (double B-frag set, ~160 VGPR weights). flat_work_group_size
// + waves_per_eu(2,2) (NO launch_bounds -- R2 vs R8 evidence) -> 256-VGPR
// budget at 2 waves/SIMD. SIMD s hosts wave s (A) + wave s+4 (B) at OPPOSITE
// phases -> cross-phase stall interleave. Parity schedule as R12.

typedef _Float16 half8 __attribute__((ext_vector_type(8)));
typedef float f32x4 __attribute__((ext_vector_type(4)));

#define T_STEPS 1024
#define OBS 32
#define H 128
#define A_DIM 8
#define NT 512       // 8 waves: A = waves 0-3, B = waves 4-7
#define NBLK 64
#define GR 2         // rows per group

#define ZIN_P 164    // stride 82 words (mod 32 = 18) -> <=2-way banks
#define ZF_P 132     // stride 66 words (mod 32 = 2)

__device__ __forceinline__ float fexp2(float x) { return __builtin_amdgcn_exp2f(x); }
__device__ __forceinline__ float frcp(float x) { return __builtin_amdgcn_rcpf(x); }

// LDS-visibility barrier (no vmcnt drain; validated R10)
__device__ __forceinline__ void sync_lds() {
    __builtin_amdgcn_sched_barrier(0);
    asm volatile("s_waitcnt lgkmcnt(0)" ::: "memory");
    __builtin_amdgcn_s_barrier();
    __builtin_amdgcn_sched_barrier(0);
}

__attribute__((amdgpu_flat_work_group_size(NT, NT), amdgpu_waves_per_eu(2, 2)))
__global__ void cfc_kernel(
    const float* __restrict__ obs,
    const float* __restrict__ Wb,  const float* __restrict__ bb,
    const float* __restrict__ Wff1, const float* __restrict__ bff1,
    const float* __restrict__ Wff2, const float* __restrict__ bff2,
    const float* __restrict__ Wta, const float* __restrict__ bta,
    const float* __restrict__ Wtb, const float* __restrict__ btb,
    const float* __restrict__ Wa,  const float* __restrict__ ba,
    const float* __restrict__ Wc,  const float* __restrict__ bc,
    float* __restrict__ out_mean, float* __restrict__ out_value)
{
    const int tid = threadIdx.x;
    const int w = tid >> 6, l = tid & 63;
    const int g = w >> 2, wg = w & 3;        // group, wave-in-group
    const int lo = l & 15, hi = l >> 4;
    const int b0g = blockIdx.x * 4 + g * GR;

    __shared__ _Float16 zin[2][16][ZIN_P];   // per-group [x_t | h]
    __shared__ _Float16 zf[2][16][ZF_P];     // per-group z

    // -------- preload B-fragments: wave owns cols [32wg, 32wg+32) ---------
    half8 Bb[2][5];
    half8 Bg0[2][4], Bg1[2][4], Bg2[2][4];
    float bbv[2], bg1v[2], bg2v[2], bg3v[2];
#pragma unroll
    for (int u = 0; u < 2; ++u) {
        const int colB = wg * 32 + u * 16 + lo;
#pragma unroll
        for (int ks = 0; ks < 5; ++ks)
#pragma unroll
            for (int j = 0; j < 8; ++j) {
                int k = ks * 32 + hi * 8 + j;
                Bb[u][ks][j] = (_Float16)Wb[k * H + colB];
            }
        bbv[u] = bb[colB];
#pragma unroll
        for (int ks = 0; ks < 4; ++ks)
#pragma unroll
            for (int j = 0; j < 8; ++j) {
                int k = ks * 32 + hi * 8 + j;
                Bg0[u][ks][j] = (_Float16)Wff1[k * H + colB];
                Bg1[u][ks][j] = (_Float16)Wff2[k * H + colB];
                Bg2[u][ks][j] = (_Float16)(Wta[k * H + colB] + Wtb[k * H + colB]);
            }
        bg1v[u] = bff1[colB];
        bg2v[u] = bff2[colB];
        bg3v[u] = bta[colB] + btb[colB];
    }

    half8 Bh[4];                              // heads (wg==3 wave of each group)
    float bh = 0.f;
    if (wg == 3) {
#pragma unroll
        for (int ks = 0; ks < 4; ++ks)
#pragma unroll
            for (int j = 0; j < 8; ++j) {
                int k = ks * 32 + hi * 8 + j;
                float v = (lo < 8) ? Wa[k * A_DIM + lo] : ((lo == 8) ? Wc[k] : 0.0f);
                Bh[ks][j] = (_Float16)v;
            }
        bh = (lo < 8) ? ba[lo] : ((lo == 8) ? bc[0] : 0.0f);
    }

    // -------- x ring (wg==0 wave of each group; 2 rows) --------
    const int rx = l >> 5, cx = l & 31;
    const float* obsrow = obs + ((size_t)(b0g + rx) * T_STEPS) * OBS;
    float oxA = 0.f, oxB = 0.f;

    // -------- init LDS --------
    for (int i = tid; i < 2 * 16 * ZIN_P; i += NT) (&zin[0][0][0])[i] = (_Float16)0.0f;
    __syncthreads();
    if (wg == 0) {
        zin[g][rx][cx] = (_Float16)obsrow[cx];   // x(0)
        oxA = obsrow[OBS + cx];                  // x(1)
        oxB = obsrow[2 * OBS + cx];              // x(2)
    }
    __syncthreads();

    // ================= interval loop (parity schedule, verified R12) ======
    for (int iv = -1; iv < 2 * T_STEPS; ++iv) {
        const bool doP1 = ((iv ^ g) & 1) == 0;
        if (doP1) {
            const int t = (iv + g) >> 1;
            half8 A0 = *(const half8*)&zin[g][lo][0 * 32 + hi * 8];
            half8 A1 = *(const half8*)&zin[g][lo][1 * 32 + hi * 8];
            half8 A2 = *(const half8*)&zin[g][lo][2 * 32 + hi * 8];
            half8 A3 = *(const half8*)&zin[g][lo][3 * 32 + hi * 8];
            half8 A4 = *(const half8*)&zin[g][lo][4 * 32 + hi * 8];
#pragma unroll
            for (int u = 0; u < 2; ++u) {
                f32x4 az0 = {bbv[u], bbv[u], bbv[u], bbv[u]};
                f32x4 az1 = {0.f, 0.f, 0.f, 0.f};
                az0 = __builtin_amdgcn_mfma_f32_16x16x32_f16(A0, Bb[u][0], az0, 0, 0, 0);
                az1 = __builtin_amdgcn_mfma_f32_16x16x32_f16(A1, Bb[u][1], az1, 0, 0, 0);
                az0 = __builtin_amdgcn_mfma_f32_16x16x32_f16(A2, Bb[u][2], az0, 0, 0, 0);
                az1 = __builtin_amdgcn_mfma_f32_16x16x32_f16(A3, Bb[u][3], az1, 0, 0, 0);
                az0 = __builtin_amdgcn_mfma_f32_16x16x32_f16(A4, Bb[u][4], az0, 0, 0, 0);
#pragma unroll
                for (int j = 0; j < 4; ++j) {
                    float s = az0[j] + az1[j];
                    float r = frcp(fexp2(1.9216697f * s) + 1.0f);
                    zf[g][hi * 4 + j][wg * 32 + u * 16 + lo] = (_Float16)fmaf(-3.4318f, r, 1.7159f);
                }
            }

            // heads on h(t-1) (A1..A4 are the h k-subtiles)
            if (wg == 3 && t >= 1) {
                f32x4 acch = {bh, bh, bh, bh};
                acch = __builtin_amdgcn_mfma_f32_16x16x32_f16(A1, Bh[0], acch, 0, 0, 0);
                acch = __builtin_amdgcn_mfma_f32_16x16x32_f16(A2, Bh[1], acch, 0, 0, 0);
                acch = __builtin_amdgcn_mfma_f32_16x16x32_f16(A3, Bh[2], acch, 0, 0, 0);
                acch = __builtin_amdgcn_mfma_f32_16x16x32_f16(A4, Bh[3], acch, 0, 0, 0);
                if (hi == 0 && lo < 9) {
                    const int s_ = t - 1;
#pragma unroll
                    for (int j = 0; j < GR; ++j) {
                        if (lo < 8) out_mean[((size_t)(b0g + j) * T_STEPS + s_) * A_DIM + lo] = acch[j];
                        else        out_value[(size_t)(b0g + j) * T_STEPS + s_] = acch[j];
                    }
                }
            }
        } else {
            const int t = iv >> 1;
            if (t >= 0) {
                half8 Z0 = *(const half8*)&zf[g][lo][0 * 32 + hi * 8];
                half8 Z1 = *(const half8*)&zf[g][lo][1 * 32 + hi * 8];
                half8 Z2 = *(const half8*)&zf[g][lo][2 * 32 + hi * 8];
                half8 Z3 = *(const half8*)&zf[g][lo][3 * 32 + hi * 8];
#pragma unroll
                for (int u = 0; u < 2; ++u) {
                    f32x4 a1 = {bg1v[u], bg1v[u], bg1v[u], bg1v[u]};
                    f32x4 a2 = {bg2v[u], bg2v[u], bg2v[u], bg2v[u]};
                    f32x4 a3 = {bg3v[u], bg3v[u], bg3v[u], bg3v[u]};
                    a1 = __builtin_amdgcn_mfma_f32_16x16x32_f16(Z0, Bg0[u][0], a1, 0, 0, 0);
                    a2 = __builtin_amdgcn_mfma_f32_16x16x32_f16(Z0, Bg1[u][0], a2, 0, 0, 0);
                    a3 = __builtin_amdgcn_mfma_f32_16x16x32_f16(Z0, Bg2[u][0], a3, 0, 0, 0);
                    a1 = __builtin_amdgcn_mfma_f32_16x16x32_f16(Z1, Bg0[u][1], a1, 0, 0, 0);
                    a2 = __builtin_amdgcn_mfma_f32_16x16x32_f16(Z1, Bg1[u][1], a2, 0, 0, 0);
                    a3 = __builtin_amdgcn_mfma_f32_16x16x32_f16(Z1, Bg2[u][1], a3, 0, 0, 0);
                    a1 = __builtin_amdgcn_mfma_f32_16x16x32_f16(Z2, Bg0[u][2], a1, 0, 0, 0);
                    a2 = __builtin_amdgcn_mfma_f32_16x16x32_f16(Z2, Bg1[u][2], a2, 0, 0, 0);
                    a3 = __builtin_amdgcn_mfma_f32_16x16x32_f16(Z2, Bg2[u][2], a3, 0, 0, 0);
                    a1 = __builtin_amdgcn_mfma_f32_16x16x32_f16(Z3, Bg0[u][3], a1, 0, 0, 0);
                    a2 = __builtin_amdgcn_mfma_f32_16x16x32_f16(Z3, Bg1[u][3], a2, 0, 0, 0);
                    a3 = __builtin_amdgcn_mfma_f32_16x16x32_f16(Z3, Bg2[u][3], a3, 0, 0, 0);
#pragma unroll
                    for (int j = 0; j < 4; ++j) {
                        float r1 = frcp(fexp2(2.8853901f * a1[j]) + 1.0f);
                        float ff1 = fmaf(-2.0f, r1, 1.0f);
                        float r2 = frcp(fexp2(2.8853901f * a2[j]) + 1.0f);
                        float ff2 = fmaf(-2.0f, r2, 1.0f);
                        float ti = frcp(1.0f + fexp2(-1.44269504f * a3[j]));
                        zin[g][hi * 4 + j][32 + wg * 32 + u * 16 + lo] = (_Float16)(ff1 + ti * (ff2 - ff1));
                    }
                }

                // x(t+1) write + 2-deep ring refill (this group's wg==0 wave)
                if (wg == 0) {
                    if (t + 1 < T_STEPS) zin[g][rx][cx] = (_Float16)oxA;
                    oxA = oxB;
                    const int tf = t + 3;
                    oxB = (tf < T_STEPS) ? obsrow[(size_t)tf * OBS + cx] : 0.0f;
                }
            }
        }
        sync_lds();
    }

    // ---- epilogue: group A heads for s = T-1 (B's covered in-loop) ----
    if (g == 0 && wg == 3) {
        half8 A1 = *(const half8*)&zin[0][lo][32 + 0 * 32 + hi * 8];
        half8 A2 = *(const half8*)&zin[0][lo][32 + 1 * 32 + hi * 8];
        half8 A3 = *(const half8*)&zin[0][lo][32 + 2 * 32 + hi * 8];
        half8 A4 = *(const half8*)&zin[0][lo][32 + 3 * 32 + hi * 8];
        f32x4 acch = {bh, bh, bh, bh};
        acch = __builtin_amdgcn_mfma_f32_16x16x32_f16(A1, Bh[0], acch, 0, 0, 0);
        acch = __builtin_amdgcn_mfma_f32_16x16x32_f16(A2, Bh[1], acch, 0, 0, 0);
        acch = __builtin_amdgcn_mfma_f32_16x16x32_f16(A3, Bh[2], acch, 0, 0, 0);
        acch = __builtin_amdgcn_mfma_f32_16x16x32_f16(A4, Bh[3], acch, 0, 0, 0);
        if (hi == 0 && lo < 9) {
#pragma unroll
            for (int j = 0; j < GR; ++j) {
                if (lo < 8) out_mean[((size_t)(b0g + j) * T_STEPS + (T_STEPS - 1)) * A_DIM + lo] = acch[j];
                else        out_value[(size_t)(b0g + j) * T_STEPS + (T_STEPS - 1)] = acch[j];
            }
        }
    }
}

extern "C" void kernel_launch(void* const* d_in, const int* in_sizes, int n_in,
                              void* d_out, int out_size, void* d_ws, size_t ws_size,
                              hipStream_t stream) {
    (void)in_sizes; (void)n_in; (void)d_ws; (void)ws_size; (void)out_size;
    const float* obs  = (const float*)d_in[0];
    const float* Wb   = (const float*)d_in[1];
    const float* bb   = (const float*)d_in[2];
    const float* Wff1 = (const float*)d_in[3];
    const float* bff1 = (const float*)d_in[4];
    const float* Wff2 = (const float*)d_in[5];
    const float* bff2 = (const float*)d_in[6];
    const float* Wta  = (const float*)d_in[7];
    const float* bta  = (const float*)d_in[8];
    const float* Wtb  = (const float*)d_in[9];
    const float* btb  = (const float*)d_in[10];
    const float* Wa   = (const float*)d_in[11];
    const float* ba   = (const float*)d_in[12];
    const float* Wc   = (const float*)d_in[13];
    const float* bc   = (const float*)d_in[14];
    float* out = (float*)d_out;
    float* out_mean  = out;
    float* out_value = out + (size_t)256 * 1024 * 8;

    cfc_kernel<<<dim3(NBLK), dim3(NT), 0, stream>>>(
        obs, Wb, bb, Wff1, bff1, Wff2, bff2, Wta, bta, Wtb, btb,
        Wa, ba, Wc, bc, out_mean, out_value);
}

// Round 14
// 1082.196 us; speedup vs baseline: 4.7416x; 1.9169x over previous
//
#include <hip/hip_runtime.h>

// CfC actor-critic forward: B=256, T=1024, OBS=32, H=128, A=8.
// R14 = R9/R10 base + heads OFFLOADED out of the sequential loop:
//  - every step, each wave stores its h C-frag slice (rows 0-3) as f16 into a
//    67MB history in d_ws (fire-and-forget scalar stores, no vmcnt drain at
//    the lgkm-only barrier),
//  - after the T-loop the same block runs a heads-GEMM epilogue over its own
//    4 rows x 1024 steps (M-dim = steps, 16 steps/tile, 32 iters/wave).
// Rationale: wave 7's in-loop head chain (4 dependent MFMAs + stores) was the
// barrier straggler at EVERY interval. Fallback to in-loop heads if ws_size
// is too small (template<OFFLOAD>).

typedef _Float16 half8 __attribute__((ext_vector_type(8)));
typedef float f32x4 __attribute__((ext_vector_type(4)));

#define T_STEPS 1024
#define OBS 32
#define H 128
#define A_DIM 8
#define NW 8
#define NT (NW * 64)
#define ROWS 4
#define NBLK 64

#define ZIN_P 164   // stride 82 words (mod 32 = 18) -> <=2-way banks
#define ZF_P 132    // stride 66 words (mod 32 = 2)

__device__ __forceinline__ float fexp2(float x) { return __builtin_amdgcn_exp2f(x); }
__device__ __forceinline__ float frcp(float x) { return __builtin_amdgcn_rcpf(x); }

// LDS-visibility barrier (no vmcnt drain; validated R10)
__device__ __forceinline__ void sync_lds() {
    __builtin_amdgcn_sched_barrier(0);
    asm volatile("s_waitcnt lgkmcnt(0)" ::: "memory");
    __builtin_amdgcn_s_barrier();
    __builtin_amdgcn_sched_barrier(0);
}

template<bool OFFLOAD>
__global__ void __launch_bounds__(NT) cfc_kernel(
    const float* __restrict__ obs,
    const float* __restrict__ Wb,  const float* __restrict__ bb,
    const float* __restrict__ Wff1, const float* __restrict__ bff1,
    const float* __restrict__ Wff2, const float* __restrict__ bff2,
    const float* __restrict__ Wta, const float* __restrict__ bta,
    const float* __restrict__ Wtb, const float* __restrict__ btb,
    const float* __restrict__ Wa,  const float* __restrict__ ba,
    const float* __restrict__ Wc,  const float* __restrict__ bc,
    float* __restrict__ out_mean, float* __restrict__ out_value,
    _Float16* __restrict__ hist)
{
    const int b0 = blockIdx.x * ROWS;
    const int tid = threadIdx.x;
    const int w = tid >> 6, l = tid & 63;
    const int lo = l & 15, hi = l >> 4;      // lo: M/N index, hi: k-group

    __shared__ _Float16 zin[16][ZIN_P];      // [x_t | h_{t-1}]
    __shared__ _Float16 zf[16][ZF_P];        // z(t)

    // ---------------- preload B-fragments (f16) ----------------
    const int colB = w * 16 + lo;

    half8 Bb[5];                              // backbone 160xH
#pragma unroll
    for (int ks = 0; ks < 5; ++ks)
#pragma unroll
        for (int j = 0; j < 8; ++j) {
            int k = ks * 32 + hi * 8 + j;
            Bb[ks][j] = (_Float16)Wb[k * H + colB];
        }
    const float bbv = bb[colB];

    half8 Bg0[4], Bg1[4], Bg2[4];             // gates HxH
#pragma unroll
    for (int ks = 0; ks < 4; ++ks)
#pragma unroll
        for (int j = 0; j < 8; ++j) {
            int k = ks * 32 + hi * 8 + j;
            Bg0[ks][j] = (_Float16)Wff1[k * H + colB];
            Bg1[ks][j] = (_Float16)Wff2[k * H + colB];
            Bg2[ks][j] = (_Float16)(Wta[k * H + colB] + Wtb[k * H + colB]);
        }
    const float bg1 = bff1[colB], bg2 = bff2[colB], bg3 = bta[colB] + btb[colB];

    // In-loop heads only for the fallback path (wave 7)
    half8 Bh[4];
    float bh = 0.f;
    if (!OFFLOAD && w == 7) {
#pragma unroll
        for (int ks = 0; ks < 4; ++ks)
#pragma unroll
            for (int j = 0; j < 8; ++j) {
                int k = ks * 32 + hi * 8 + j;
                float v = (lo < 8) ? Wa[k * A_DIM + lo] : ((lo == 8) ? Wc[k] : 0.0f);
                Bh[ks][j] = (_Float16)v;
            }
        bh = (lo < 8) ? ba[lo] : ((lo == 8) ? bc[0] : 0.0f);
    }

    // ---------------- init LDS ----------------
    for (int i = tid; i < 16 * ZIN_P; i += NT) (&zin[0][0])[i] = (_Float16)0.0f;
    __syncthreads();
    const int rX = (w << 1) | (l >> 5), cX = l & 31;   // waves 0-1: rows 0-3
    if (w < 2) zin[rX][cX] = (_Float16)obs[((size_t)(b0 + rX) * T_STEPS) * OBS + cX];
    __syncthreads();

    // obs prefetch ring, 2 steps deep (waves 0-1)
    float oxA = 0.f, oxB = 0.f;
    if (w < 2) {
        oxA = obs[((size_t)(b0 + rX) * T_STEPS + 1) * OBS + cX];
        oxB = obs[((size_t)(b0 + rX) * T_STEPS + 2) * OBS + cX];
    }

    // ================= main loop: 2 LDS-only barriers/step =================
    for (int t = 0; t < T_STEPS; ++t) {
        // ---- phase 1: z = lecun_tanh([x|h] @ Wb + bb) ----
        half8 A0 = *(const half8*)&zin[lo][0 * 32 + hi * 8];
        half8 A1 = *(const half8*)&zin[lo][1 * 32 + hi * 8];
        half8 A2 = *(const half8*)&zin[lo][2 * 32 + hi * 8];
        half8 A3 = *(const half8*)&zin[lo][3 * 32 + hi * 8];
        half8 A4 = *(const half8*)&zin[lo][4 * 32 + hi * 8];
        f32x4 az0 = {bbv, bbv, bbv, bbv};
        f32x4 az1 = {0.f, 0.f, 0.f, 0.f};
        az0 = __builtin_amdgcn_mfma_f32_16x16x32_f16(A0, Bb[0], az0, 0, 0, 0);
        az1 = __builtin_amdgcn_mfma_f32_16x16x32_f16(A1, Bb[1], az1, 0, 0, 0);
        az0 = __builtin_amdgcn_mfma_f32_16x16x32_f16(A2, Bb[2], az0, 0, 0, 0);
        az1 = __builtin_amdgcn_mfma_f32_16x16x32_f16(A3, Bb[3], az1, 0, 0, 0);
        az0 = __builtin_amdgcn_mfma_f32_16x16x32_f16(A4, Bb[4], az0, 0, 0, 0);

        if (!OFFLOAD && w == 7 && t > 0) {
            f32x4 acch = {bh, bh, bh, bh};
            acch = __builtin_amdgcn_mfma_f32_16x16x32_f16(A1, Bh[0], acch, 0, 0, 0);
            acch = __builtin_amdgcn_mfma_f32_16x16x32_f16(A2, Bh[1], acch, 0, 0, 0);
            acch = __builtin_amdgcn_mfma_f32_16x16x32_f16(A3, Bh[2], acch, 0, 0, 0);
            acch = __builtin_amdgcn_mfma_f32_16x16x32_f16(A4, Bh[3], acch, 0, 0, 0);
            if (hi == 0 && lo < 9) {
#pragma unroll
                for (int j = 0; j < 4; ++j) {
                    if (lo < 8) out_mean[((size_t)(b0 + j) * T_STEPS + (t - 1)) * A_DIM + lo] = acch[j];
                    else        out_value[(size_t)(b0 + j) * T_STEPS + (t - 1)] = acch[j];
                }
            }
        }

        // z-act -> zf: 1.7159*tanh(0.666x) = 1.7159 - 3.4318/(2^(1.9216697x)+1)
#pragma unroll
        for (int j = 0; j < 4; ++j) {
            float s = az0[j] + az1[j];
            float r = frcp(fexp2(1.9216697f * s) + 1.0f);
            zf[hi * 4 + j][colB] = (_Float16)fmaf(-3.4318f, r, 1.7159f);
        }
        sync_lds();

        // ---- phase 2: gates + combine -> h(t) ----
        half8 Z0 = *(const half8*)&zf[lo][0 * 32 + hi * 8];
        half8 Z1 = *(const half8*)&zf[lo][1 * 32 + hi * 8];
        half8 Z2 = *(const half8*)&zf[lo][2 * 32 + hi * 8];
        half8 Z3 = *(const half8*)&zf[lo][3 * 32 + hi * 8];
        f32x4 a1 = {bg1, bg1, bg1, bg1};
        f32x4 a2 = {bg2, bg2, bg2, bg2};
        f32x4 a3 = {bg3, bg3, bg3, bg3};
        a1 = __builtin_amdgcn_mfma_f32_16x16x32_f16(Z0, Bg0[0], a1, 0, 0, 0);
        a2 = __builtin_amdgcn_mfma_f32_16x16x32_f16(Z0, Bg1[0], a2, 0, 0, 0);
        a3 = __builtin_amdgcn_mfma_f32_16x16x32_f16(Z0, Bg2[0], a3, 0, 0, 0);
        a1 = __builtin_amdgcn_mfma_f32_16x16x32_f16(Z1, Bg0[1], a1, 0, 0, 0);
        a2 = __builtin_amdgcn_mfma_f32_16x16x32_f16(Z1, Bg1[1], a2, 0, 0, 0);
        a3 = __builtin_amdgcn_mfma_f32_16x16x32_f16(Z1, Bg2[1], a3, 0, 0, 0);
        a1 = __builtin_amdgcn_mfma_f32_16x16x32_f16(Z2, Bg0[2], a1, 0, 0, 0);
        a2 = __builtin_amdgcn_mfma_f32_16x16x32_f16(Z2, Bg1[2], a2, 0, 0, 0);
        a3 = __builtin_amdgcn_mfma_f32_16x16x32_f16(Z2, Bg2[2], a3, 0, 0, 0);
        a1 = __builtin_amdgcn_mfma_f32_16x16x32_f16(Z3, Bg0[3], a1, 0, 0, 0);
        a2 = __builtin_amdgcn_mfma_f32_16x16x32_f16(Z3, Bg1[3], a2, 0, 0, 0);
        a3 = __builtin_amdgcn_mfma_f32_16x16x32_f16(Z3, Bg2[3], a3, 0, 0, 0);

#pragma unroll
        for (int j = 0; j < 4; ++j) {
            float r1 = frcp(fexp2(2.8853901f * a1[j]) + 1.0f);
            float ff1 = fmaf(-2.0f, r1, 1.0f);
            float r2 = frcp(fexp2(2.8853901f * a2[j]) + 1.0f);
            float ff2 = fmaf(-2.0f, r2, 1.0f);
            float ti = frcp(1.0f + fexp2(-1.44269504f * a3[j]));
            _Float16 hv = (_Float16)(ff1 + ti * (ff2 - ff1));
            zin[hi * 4 + j][32 + colB] = hv;
            if (OFFLOAD && hi == 0)   // rows 0-3 only: h-history, fire-and-forget
                hist[((size_t)(b0 + j) * T_STEPS + t) * H + colB] = hv;
        }

        // x(t+1) -> zin (waves 0-1), refill 2-deep ring
        if (w < 2 && t + 1 < T_STEPS) {
            zin[rX][cX] = (_Float16)oxA;
            oxA = oxB;
            const int tf = t + 3;
            oxB = (tf < T_STEPS) ? obs[((size_t)(b0 + rX) * T_STEPS + tf) * OBS + cX] : 0.0f;
        }
        sync_lds();
    }

    if (OFFLOAD) {
        // ---- epilogue: heads GEMM over this block's 4 rows x 1024 steps ----
        __syncthreads();                      // drains vmcnt: hist visible
        half8 Bh2[4];
#pragma unroll
        for (int ks = 0; ks < 4; ++ks)
#pragma unroll
            for (int j = 0; j < 8; ++j) {
                int k = ks * 32 + hi * 8 + j;
                float v = (lo < 8) ? Wa[k * A_DIM + lo] : ((lo == 8) ? Wc[k] : 0.0f);
                Bh2[ks][j] = (_Float16)v;
            }
        const float bh2 = (lo < 8) ? ba[lo] : ((lo == 8) ? bc[0] : 0.0f);

        for (int c = w; c < 256; c += NW) {   // 32 chunks per wave
            const int r = c >> 6;             // row 0..3
            const int s0 = (c & 63) << 4;     // step base (16 steps per tile)
            const _Float16* hp = hist + ((size_t)(b0 + r) * T_STEPS + (s0 + lo)) * H + hi * 8;
            half8 A0 = *(const half8*)(hp);
            half8 A1 = *(const half8*)(hp + 32);
            half8 A2 = *(const half8*)(hp + 64);
            half8 A3 = *(const half8*)(hp + 96);
            f32x4 acc = {bh2, bh2, bh2, bh2};
            acc = __builtin_amdgcn_mfma_f32_16x16x32_f16(A0, Bh2[0], acc, 0, 0, 0);
            acc = __builtin_amdgcn_mfma_f32_16x16x32_f16(A1, Bh2[1], acc, 0, 0, 0);
            acc = __builtin_amdgcn_mfma_f32_16x16x32_f16(A2, Bh2[2], acc, 0, 0, 0);
            acc = __builtin_amdgcn_mfma_f32_16x16x32_f16(A3, Bh2[3], acc, 0, 0, 0);
            if (lo < 9) {
#pragma unroll
                for (int j = 0; j < 4; ++j) {
                    const int s_ = s0 + hi * 4 + j;    // C-frag row = step offset
                    if (lo < 8) out_mean[((size_t)(b0 + r) * T_STEPS + s_) * A_DIM + lo] = acc[j];
                    else        out_value[(size_t)(b0 + r) * T_STEPS + s_] = acc[j];
                }
            }
        }
    } else {
        // ---- fallback epilogue: heads for s = T-1 ----
        if (w == 7) {
            half8 A1 = *(const half8*)&zin[lo][32 + 0 * 32 + hi * 8];
            half8 A2 = *(const half8*)&zin[lo][32 + 1 * 32 + hi * 8];
            half8 A3 = *(const half8*)&zin[lo][32 + 2 * 32 + hi * 8];
            half8 A4 = *(const half8*)&zin[lo][32 + 3 * 32 + hi * 8];
            f32x4 acch = {bh, bh, bh, bh};
            acch = __builtin_amdgcn_mfma_f32_16x16x32_f16(A1, Bh[0], acch, 0, 0, 0);
            acch = __builtin_amdgcn_mfma_f32_16x16x32_f16(A2, Bh[1], acch, 0, 0, 0);
            acch = __builtin_amdgcn_mfma_f32_16x16x32_f16(A3, Bh[2], acch, 0, 0, 0);
            acch = __builtin_amdgcn_mfma_f32_16x16x32_f16(A4, Bh[3], acch, 0, 0, 0);
            if (hi == 0 && lo < 9) {
#pragma unroll
                for (int j = 0; j < 4; ++j) {
                    if (lo < 8) out_mean[((size_t)(b0 + j) * T_STEPS + (T_STEPS - 1)) * A_DIM + lo] = acch[j];
                    else        out_value[(size_t)(b0 + j) * T_STEPS + (T_STEPS - 1)] = acch[j];
                }
            }
        }
    }
}

extern "C" void kernel_launch(void* const* d_in, const int* in_sizes, int n_in,
                              void* d_out, int out_size, void* d_ws, size_t ws_size,
                              hipStream_t stream) {
    (void)in_sizes; (void)n_in; (void)out_size;
    const float* obs  = (const float*)d_in[0];
    const float* Wb   = (const float*)d_in[1];
    const float* bb   = (const float*)d_in[2];
    const float* Wff1 = (const float*)d_in[3];
    const float* bff1 = (const float*)d_in[4];
    const float* Wff2 = (const float*)d_in[5];
    const float* bff2 = (const float*)d_in[6];
    const float* Wta  = (const float*)d_in[7];
    const float* bta  = (const float*)d_in[8];
    const float* Wtb  = (const float*)d_in[9];
    const float* btb  = (const float*)d_in[10];
    const float* Wa   = (const float*)d_in[11];
    const float* ba   = (const float*)d_in[12];
    const float* Wc   = (const float*)d_in[13];
    const float* bc   = (const float*)d_in[14];
    float* out = (float*)d_out;
    float* out_mean  = out;
    float* out_value = out + (size_t)256 * 1024 * 8;

    const size_t need = (size_t)256 * 1024 * 128 * sizeof(_Float16);  // 67.1 MB
    if (ws_size >= need) {
        cfc_kernel<true><<<dim3(NBLK), dim3(NT), 0, stream>>>(
            obs, Wb, bb, Wff1, bff1, Wff2, bff2, Wta, bta, Wtb, btb,
            Wa, ba, Wc, bc, out_mean, out_value, (_Float16*)d_ws);
    } else {
        cfc_kernel<false><<<dim3(NBLK), dim3(NT), 0, stream>>>(
            obs, Wb, bb, Wff1, bff1, Wff2, bff2, Wta, bta, Wtb, btb,
            Wa, ba, Wc, bc, out_mean, out_value, (_Float16*)d_ws);
    }
}

// Round 15
// 1011.185 us; speedup vs baseline: 5.0746x; 1.0702x over previous
//
#include <hip/hip_runtime.h>

// CfC actor-critic forward: B=256, T=1024, OBS=32, H=128, A=8.
// R15 = R14 + activation redistribution: the M=16 tile holds only 4 real
// batch rows, so per-thread activations (12 exp2 + 12 rcp in ph2) were 4x
// redundant and the quarter-rate trans unit serialized ~192 cyc/SIMD on the
// critical path. Redistribute the 64 real (col,row) values across all 64
// lanes via __shfl (ds_bpermute) + selects -> ONE activation chain per lane.
// Garbage rows 4-15 are no longer activated OR written (stay zero; MFMA
// M-rows are independent so they never contaminate real outputs).

typedef _Float16 half8 __attribute__((ext_vector_type(8)));
typedef float f32x4 __attribute__((ext_vector_type(4)));

#define T_STEPS 1024
#define OBS 32
#define H 128
#define A_DIM 8
#define NW 8
#define NT (NW * 64)
#define ROWS 4
#define NBLK 64

#define ZIN_P 164   // stride 82 words (mod 32 = 18) -> <=2-way banks
#define ZF_P 132    // stride 66 words (mod 32 = 2)

__device__ __forceinline__ float fexp2(float x) { return __builtin_amdgcn_exp2f(x); }
__device__ __forceinline__ float frcp(float x) { return __builtin_amdgcn_rcpf(x); }

// LDS-visibility barrier (no vmcnt drain; validated R10)
__device__ __forceinline__ void sync_lds() {
    __builtin_amdgcn_sched_barrier(0);
    asm volatile("s_waitcnt lgkmcnt(0)" ::: "memory");
    __builtin_amdgcn_s_barrier();
    __builtin_amdgcn_sched_barrier(0);
}

template<bool OFFLOAD>
__global__ void __launch_bounds__(NT) cfc_kernel(
    const float* __restrict__ obs,
    const float* __restrict__ Wb,  const float* __restrict__ bb,
    const float* __restrict__ Wff1, const float* __restrict__ bff1,
    const float* __restrict__ Wff2, const float* __restrict__ bff2,
    const float* __restrict__ Wta, const float* __restrict__ bta,
    const float* __restrict__ Wtb, const float* __restrict__ btb,
    const float* __restrict__ Wa,  const float* __restrict__ ba,
    const float* __restrict__ Wc,  const float* __restrict__ bc,
    float* __restrict__ out_mean, float* __restrict__ out_value,
    _Float16* __restrict__ hist)
{
    const int b0 = blockIdx.x * ROWS;
    const int tid = threadIdx.x;
    const int w = tid >> 6, l = tid & 63;
    const int lo = l & 15, hi = l >> 4;      // lo: M/N index, hi: k-group / row

    __shared__ _Float16 zin[16][ZIN_P];      // [x_t | h_{t-1}]
    __shared__ _Float16 zf[16][ZF_P];        // z(t)

    // ---------------- preload B-fragments (f16) ----------------
    const int colB = w * 16 + lo;

    half8 Bb[5];                              // backbone 160xH
#pragma unroll
    for (int ks = 0; ks < 5; ++ks)
#pragma unroll
        for (int j = 0; j < 8; ++j) {
            int k = ks * 32 + hi * 8 + j;
            Bb[ks][j] = (_Float16)Wb[k * H + colB];
        }
    const float bbv = bb[colB];

    half8 Bg0[4], Bg1[4], Bg2[4];             // gates HxH
#pragma unroll
    for (int ks = 0; ks < 4; ++ks)
#pragma unroll
        for (int j = 0; j < 8; ++j) {
            int k = ks * 32 + hi * 8 + j;
            Bg0[ks][j] = (_Float16)Wff1[k * H + colB];
            Bg1[ks][j] = (_Float16)Wff2[k * H + colB];
            Bg2[ks][j] = (_Float16)(Wta[k * H + colB] + Wtb[k * H + colB]);
        }
    const float bg1 = bff1[colB], bg2 = bff2[colB], bg3 = bta[colB] + btb[colB];

    // In-loop heads only for the fallback path (wave 7)
    half8 Bh[4];
    float bh = 0.f;
    if (!OFFLOAD && w == 7) {
#pragma unroll
        for (int ks = 0; ks < 4; ++ks)
#pragma unroll
            for (int j = 0; j < 8; ++j) {
                int k = ks * 32 + hi * 8 + j;
                float v = (lo < 8) ? Wa[k * A_DIM + lo] : ((lo == 8) ? Wc[k] : 0.0f);
                Bh[ks][j] = (_Float16)v;
            }
        bh = (lo < 8) ? ba[lo] : ((lo == 8) ? bc[0] : 0.0f);
    }

    // ---------------- init LDS (zin AND zf zeroed; rows 4-15 stay zero) ---
    for (int i = tid; i < 16 * ZIN_P; i += NT) (&zin[0][0])[i] = (_Float16)0.0f;
    for (int i = tid; i < 16 * ZF_P; i += NT) (&zf[0][0])[i] = (_Float16)0.0f;
    __syncthreads();
    const int rX = (w << 1) | (l >> 5), cX = l & 31;   // waves 0-1: rows 0-3
    if (w < 2) zin[rX][cX] = (_Float16)obs[((size_t)(b0 + rX) * T_STEPS) * OBS + cX];
    __syncthreads();

    // obs prefetch ring, 2 steps deep (waves 0-1)
    float oxA = 0.f, oxB = 0.f;
    if (w < 2) {
        oxA = obs[((size_t)(b0 + rX) * T_STEPS + 1) * OBS + cX];
        oxB = obs[((size_t)(b0 + rX) * T_STEPS + 2) * OBS + cX];
    }

    const int srcl = lo;                     // shuffle source: hi==0 lane of same col

    // ================= main loop: 2 LDS-only barriers/step =================
    for (int t = 0; t < T_STEPS; ++t) {
        // ---- phase 1: z = lecun_tanh([x|h] @ Wb + bb) ----
        half8 A0 = *(const half8*)&zin[lo][0 * 32 + hi * 8];
        half8 A1 = *(const half8*)&zin[lo][1 * 32 + hi * 8];
        half8 A2 = *(const half8*)&zin[lo][2 * 32 + hi * 8];
        half8 A3 = *(const half8*)&zin[lo][3 * 32 + hi * 8];
        half8 A4 = *(const half8*)&zin[lo][4 * 32 + hi * 8];
        f32x4 az0 = {bbv, bbv, bbv, bbv};
        f32x4 az1 = {0.f, 0.f, 0.f, 0.f};
        az0 = __builtin_amdgcn_mfma_f32_16x16x32_f16(A0, Bb[0], az0, 0, 0, 0);
        az1 = __builtin_amdgcn_mfma_f32_16x16x32_f16(A1, Bb[1], az1, 0, 0, 0);
        az0 = __builtin_amdgcn_mfma_f32_16x16x32_f16(A2, Bb[2], az0, 0, 0, 0);
        az1 = __builtin_amdgcn_mfma_f32_16x16x32_f16(A3, Bb[3], az1, 0, 0, 0);
        az0 = __builtin_amdgcn_mfma_f32_16x16x32_f16(A4, Bb[4], az0, 0, 0, 0);

        if (!OFFLOAD && w == 7 && t > 0) {
            f32x4 acch = {bh, bh, bh, bh};
            acch = __builtin_amdgcn_mfma_f32_16x16x32_f16(A1, Bh[0], acch, 0, 0, 0);
            acch = __builtin_amdgcn_mfma_f32_16x16x32_f16(A2, Bh[1], acch, 0, 0, 0);
            acch = __builtin_amdgcn_mfma_f32_16x16x32_f16(A3, Bh[2], acch, 0, 0, 0);
            acch = __builtin_amdgcn_mfma_f32_16x16x32_f16(A4, Bh[3], acch, 0, 0, 0);
            if (hi == 0 && lo < 9) {
#pragma unroll
                for (int j = 0; j < 4; ++j) {
                    if (lo < 8) out_mean[((size_t)(b0 + j) * T_STEPS + (t - 1)) * A_DIM + lo] = acch[j];
                    else        out_value[(size_t)(b0 + j) * T_STEPS + (t - 1)] = acch[j];
                }
            }
        }

        // z-act (redistributed): real rows live in hi==0 lanes' 4 regs;
        // spread 64 values over 64 lanes -> 1 exp2 + 1 rcp per lane.
        {
            float s0 = az0[0] + az1[0];
            float s1 = az0[1] + az1[1];
            float s2 = az0[2] + az1[2];
            float s3 = az0[3] + az1[3];
            float p0 = __shfl(s0, srcl);
            float p1 = __shfl(s1, srcl);
            float p2 = __shfl(s2, srcl);
            float p3 = __shfl(s3, srcl);
            float q01 = (hi & 1) ? p1 : p0;
            float q23 = (hi & 1) ? p3 : p2;
            float sv  = (hi & 2) ? q23 : q01;
            float r = frcp(fexp2(1.9216697f * sv) + 1.0f);
            zf[hi][colB] = (_Float16)fmaf(-3.4318f, r, 1.7159f);   // row = hi (0..3)
        }
        sync_lds();

        // ---- phase 2: gates + combine -> h(t) ----
        half8 Z0 = *(const half8*)&zf[lo][0 * 32 + hi * 8];
        half8 Z1 = *(const half8*)&zf[lo][1 * 32 + hi * 8];
        half8 Z2 = *(const half8*)&zf[lo][2 * 32 + hi * 8];
        half8 Z3 = *(const half8*)&zf[lo][3 * 32 + hi * 8];
        f32x4 a1 = {bg1, bg1, bg1, bg1};
        f32x4 a2 = {bg2, bg2, bg2, bg2};
        f32x4 a3 = {bg3, bg3, bg3, bg3};
        a1 = __builtin_amdgcn_mfma_f32_16x16x32_f16(Z0, Bg0[0], a1, 0, 0, 0);
        a2 = __builtin_amdgcn_mfma_f32_16x16x32_f16(Z0, Bg1[0], a2, 0, 0, 0);
        a3 = __builtin_amdgcn_mfma_f32_16x16x32_f16(Z0, Bg2[0], a3, 0, 0, 0);
        a1 = __builtin_amdgcn_mfma_f32_16x16x32_f16(Z1, Bg0[1], a1, 0, 0, 0);
        a2 = __builtin_amdgcn_mfma_f32_16x16x32_f16(Z1, Bg1[1], a2, 0, 0, 0);
        a3 = __builtin_amdgcn_mfma_f32_16x16x32_f16(Z1, Bg2[1], a3, 0, 0, 0);
        a1 = __builtin_amdgcn_mfma_f32_16x16x32_f16(Z2, Bg0[2], a1, 0, 0, 0);
        a2 = __builtin_amdgcn_mfma_f32_16x16x32_f16(Z2, Bg1[2], a2, 0, 0, 0);
        a3 = __builtin_amdgcn_mfma_f32_16x16x32_f16(Z2, Bg2[2], a3, 0, 0, 0);
        a1 = __builtin_amdgcn_mfma_f32_16x16x32_f16(Z3, Bg0[3], a1, 0, 0, 0);
        a2 = __builtin_amdgcn_mfma_f32_16x16x32_f16(Z3, Bg1[3], a2, 0, 0, 0);
        a3 = __builtin_amdgcn_mfma_f32_16x16x32_f16(Z3, Bg2[3], a3, 0, 0, 0);

        // gate activations (redistributed): 3 exp2 + 3 rcp per lane total.
        {
            float p0 = __shfl(a1[0], srcl), p1 = __shfl(a1[1], srcl);
            float p2 = __shfl(a1[2], srcl), p3 = __shfl(a1[3], srcl);
            float q01 = (hi & 1) ? p1 : p0, q23 = (hi & 1) ? p3 : p2;
            float v1 = (hi & 2) ? q23 : q01;

            p0 = __shfl(a2[0], srcl); p1 = __shfl(a2[1], srcl);
            p2 = __shfl(a2[2], srcl); p3 = __shfl(a2[3], srcl);
            q01 = (hi & 1) ? p1 : p0; q23 = (hi & 1) ? p3 : p2;
            float v2 = (hi & 2) ? q23 : q01;

            p0 = __shfl(a3[0], srcl); p1 = __shfl(a3[1], srcl);
            p2 = __shfl(a3[2], srcl); p3 = __shfl(a3[3], srcl);
            q01 = (hi & 1) ? p1 : p0; q23 = (hi & 1) ? p3 : p2;
            float v3 = (hi & 2) ? q23 : q01;

            float r1 = frcp(fexp2(2.8853901f * v1) + 1.0f);
            float ff1 = fmaf(-2.0f, r1, 1.0f);
            float r2 = frcp(fexp2(2.8853901f * v2) + 1.0f);
            float ff2 = fmaf(-2.0f, r2, 1.0f);
            float ti = frcp(1.0f + fexp2(-1.44269504f * v3));
            _Float16 hv = (_Float16)(ff1 + ti * (ff2 - ff1));
            zin[hi][32 + colB] = hv;                         // row = hi (0..3)
            if (OFFLOAD)
                hist[((size_t)(b0 + hi) * T_STEPS + t) * H + colB] = hv;
        }

        // x(t+1) -> zin (waves 0-1), refill 2-deep ring
        if (w < 2 && t + 1 < T_STEPS) {
            zin[rX][cX] = (_Float16)oxA;
            oxA = oxB;
            const int tf = t + 3;
            oxB = (tf < T_STEPS) ? obs[((size_t)(b0 + rX) * T_STEPS + tf) * OBS + cX] : 0.0f;
        }
        sync_lds();
    }

    if (OFFLOAD) {
        // ---- epilogue: heads GEMM over this block's 4 rows x 1024 steps ----
        __syncthreads();                      // drains vmcnt: hist visible
        half8 Bh2[4];
#pragma unroll
        for (int ks = 0; ks < 4; ++ks)
#pragma unroll
            for (int j = 0; j < 8; ++j) {
                int k = ks * 32 + hi * 8 + j;
                float v = (lo < 8) ? Wa[k * A_DIM + lo] : ((lo == 8) ? Wc[k] : 0.0f);
                Bh2[ks][j] = (_Float16)v;
            }
        const float bh2 = (lo < 8) ? ba[lo] : ((lo == 8) ? bc[0] : 0.0f);

        for (int c = w; c < 256; c += NW) {   // 32 chunks per wave
            const int r = c >> 6;             // row 0..3
            const int s0 = (c & 63) << 4;     // step base (16 steps per tile)
            const _Float16* hp = hist + ((size_t)(b0 + r) * T_STEPS + (s0 + lo)) * H + hi * 8;
            half8 A0 = *(const half8*)(hp);
            half8 A1 = *(const half8*)(hp + 32);
            half8 A2 = *(const half8*)(hp + 64);
            half8 A3 = *(const half8*)(hp + 96);
            f32x4 acc = {bh2, bh2, bh2, bh2};
            acc = __builtin_amdgcn_mfma_f32_16x16x32_f16(A0, Bh2[0], acc, 0, 0, 0);
            acc = __builtin_amdgcn_mfma_f32_16x16x32_f16(A1, Bh2[1], acc, 0, 0, 0);
            acc = __builtin_amdgcn_mfma_f32_16x16x32_f16(A2, Bh2[2], acc, 0, 0, 0);
            acc = __builtin_amdgcn_mfma_f32_16x16x32_f16(A3, Bh2[3], acc, 0, 0, 0);
            if (lo < 9) {
#pragma unroll
                for (int j = 0; j < 4; ++j) {
                    const int s_ = s0 + hi * 4 + j;    // C-frag row = step offset
                    if (lo < 8) out_mean[((size_t)(b0 + r) * T_STEPS + s_) * A_DIM + lo] = acc[j];
                    else        out_value[(size_t)(b0 + r) * T_STEPS + s_] = acc[j];
                }
            }
        }
    } else {
        // ---- fallback epilogue: heads for s = T-1 ----
        if (w == 7) {
            half8 A1 = *(const half8*)&zin[lo][32 + 0 * 32 + hi * 8];
            half8 A2 = *(const half8*)&zin[lo][32 + 1 * 32 + hi * 8];
            half8 A3 = *(const half8*)&zin[lo][32 + 2 * 32 + hi * 8];
            half8 A4 = *(const half8*)&zin[lo][32 + 3 * 32 + hi * 8];
            f32x4 acch = {bh, bh, bh, bh};
            acch = __builtin_amdgcn_mfma_f32_16x16x32_f16(A1, Bh[0], acch, 0, 0, 0);
            acch = __builtin_amdgcn_mfma_f32_16x16x32_f16(A2, Bh[1], acch, 0, 0, 0);
            acch = __builtin_amdgcn_mfma_f32_16x16x32_f16(A3, Bh[2], acch, 0, 0, 0);
            acch = __builtin_amdgcn_mfma_f32_16x16x32_f16(A4, Bh[3], acch, 0, 0, 0);
            if (hi == 0 && lo < 9) {
#pragma unroll
                for (int j = 0; j < 4; ++j) {
                    if (lo < 8) out_mean[((size_t)(b0 + j) * T_STEPS + (T_STEPS - 1)) * A_DIM + lo] = acch[j];
                    else        out_value[(size_t)(b0 + j) * T_STEPS + (T_STEPS - 1)] = acch[j];
                }
            }
        }
    }
}

extern "C" void kernel_launch(void* const* d_in, const int* in_sizes, int n_in,
                              void* d_out, int out_size, void* d_ws, size_t ws_size,
                              hipStream_t stream) {
    (void)in_sizes; (void)n_in; (void)out_size;
    const float* obs  = (const float*)d_in[0];
    const float* Wb   = (const float*)d_in[1];
    const float* bb   = (const float*)d_in[2];
    const float* Wff1 = (const float*)d_in[3];
    const float* bff1 = (const float*)d_in[4];
    const float* Wff2 = (const float*)d_in[5];
    const float* bff2 = (const float*)d_in[6];
    const float* Wta  = (const float*)d_in[7];
    const float* bta  = (const float*)d_in[8];
    const float* Wtb  = (const float*)d_in[9];
    const float* btb  = (const float*)d_in[10];
    const float* Wa   = (const float*)d_in[11];
    const float* ba   = (const float*)d_in[12];
    const float* Wc   = (const float*)d_in[13];
    const float* bc   = (const float*)d_in[14];
    float* out = (float*)d_out;
    float* out_mean  = out;
    float* out_value = out + (size_t)256 * 1024 * 8;

    const size_t need = (size_t)256 * 1024 * 128 * sizeof(_Float16);  // 67.1 MB
    if (ws_size >= need) {
        cfc_kernel<true><<<dim3(NBLK), dim3(NT), 0, stream>>>(
            obs, Wb, bb, Wff1, bff1, Wff2, bff2, Wta, bta, Wtb, btb,
            Wa, ba, Wc, bc, out_mean, out_value, (_Float16*)d_ws);
    } else {
        cfc_kernel<false><<<dim3(NBLK), dim3(NT), 0, stream>>>(
            obs, Wb, bb, Wff1, bff1, Wff2, bff2, Wta, bta, Wtb, btb,
            Wa, ba, Wc, bc, out_mean, out_value, (_Float16*)d_ws);
    }
}